// Round 9
// baseline (66.861 us; speedup 1.0000x reference)
//
#include <hip/hip_runtime.h>
#include <hip/hip_bf16.h>
#include <math.h>

#define NN 4096
// (1/64) * log2(e)  -- folds 1/sqrt(N) and exp->exp2 conversion
#define SCL 0.022542110013890054f
#define LOG2E 1.4426950408889634f

typedef __attribute__((ext_vector_type(8))) short bf16x8;
typedef __attribute__((ext_vector_type(4))) float f32x4;
typedef __attribute__((ext_vector_type(4))) short s16x4;

__device__ __forceinline__ float exp2_fast(float x) {
  float r; asm("v_exp_f32 %0, %1" : "=v"(r) : "v"(x)); return r;
}
__device__ __forceinline__ short bf16s(float x) {
  __hip_bfloat16 b = __float2bfloat16(x);
  return *(short*)&b;
}
__device__ __forceinline__ float bf2f(unsigned short u) {
  unsigned v = (unsigned)u << 16; return *(float*)&v;
}

// ---------------------------------------------------------------------------
// Kernel 1 (fused by block range):
//   blocks [0,2048):    Wh = h@W -> fragment-major WhTf; E-tables (validated).
//   blocks [2048,2560): adj -> bits[i][g] via wave-autonomous ballot:
//     each wave packs 2 rows (4 half-rows x 32 ballots), no block barriers,
//     coalesced 256B dword reads and coalesced 256B word stores (lane l
//     ends up holding word l of the half-row: (lane>>1)==k -> words 2k,2k+1).
// ---------------------------------------------------------------------------
__global__ __launch_bounds__(256)
void k_prep(const float* __restrict__ h, const float* __restrict__ W,
            const float* __restrict__ a, const int* __restrict__ adj,
            unsigned short* __restrict__ WhTf, float2* __restrict__ Eit,
            float2* __restrict__ Ejt, unsigned* __restrict__ bits) {
  const int t = threadIdx.x;
  const int bi = blockIdx.x;
  if (bi >= 2048) {
    const int w = t >> 6, lane = t & 63;
    const int aw = (bi - 2048) * 4 + w;          // 0..2047 -> 2 rows each
#pragma unroll
    for (int half = 0; half < 4; ++half) {
      const int r = aw * 2 + (half >> 1);
      const int jb = (half & 1) * 2048;
      const int* __restrict__ src = adj + ((size_t)r << 12) + jb;
      unsigned myw = 0;
      for (int k = 0; k < 32; ++k) {
        unsigned long long m = __ballot(src[k * 64 + lane] != 0);
        if ((lane >> 1) == k)
          myw = (lane & 1) ? (unsigned)(m >> 32) : (unsigned)m;
      }
      bits[((size_t)r << 7) + (half & 1) * 64 + lane] = myw;
    }
    return;
  }
  // ---- Wh path: 8 rows (same batch) per block ----
  __shared__ float sW[4096];
  __shared__ unsigned short T[64][8];
#pragma unroll
  for (int i = 0; i < 16; ++i) sW[i * 256 + t] = W[i * 256 + t];
  __syncthreads();
  const int wv = t >> 6, lane = t & 63;
  const float a1 = a[lane], a2 = a[64 + lane];
  const int row0 = bi * 8;
  for (int r = 0; r < 2; ++r) {
    const int row = row0 + wv * 2 + r;
    const float* hr = h + (size_t)row * 64;
    float acc = 0.f;
#pragma unroll
    for (int k = 0; k < 64; ++k) acc = fmaf(hr[k], sW[k * 64 + lane], acc);
    T[lane][wv * 2 + r] = (unsigned short)bf16s(acc);
    float r1 = acc * a1, r2 = acc * a2;
#pragma unroll
    for (int sft = 32; sft; sft >>= 1) { r1 += __shfl_xor(r1, sft); r2 += __shfl_xor(r2, sft); }
    if (lane == 0) {
      const float w1s = r1 * SCL, w2s = r2 * SCL;
      Eit[row] = make_float2(exp2_fast(w1s), exp2_fast(0.2f * w1s));
      Ejt[row] = make_float2(exp2_fast(w2s), exp2_fast(0.2f * w2s));
    }
  }
  __syncthreads();
  // fragment-major store (validated): (b, ft, g, lane=rg*16+jp, e) holds
  // Wh[n = g*32 + rg*8 + e][f = ft*16 + jp].
  const int f = t >> 2, jp4 = t & 3;
  const int b = row0 >> 12, n0 = row0 & 4095;
  const int g32 = n0 >> 5, rgq = (n0 >> 3) & 3;
  unsigned v = *(unsigned*)&T[f][jp4 * 2];
  unsigned short* dst = WhTf +
      ((((size_t)(b * 4 + (f >> 4)) << 7) + g32) << 9) +
      ((rgq * 16 + (f & 15)) << 3) + jp4 * 2;
  *(unsigned*)dst = v;
}

// ---------------------------------------------------------------------------
// Kernel 2: masked-softmax attention partials via MFMA. Grid = nc x 4b x 64
// i-blocks (64 rows). Block 256 thr = 4 waves; wave w owns i-rows
// [i0+16w, i0+16w+16) and sweeps all W windows of this chunk.
// One-time LDS stages (single barrier): mask (padded [64][33]) + Ej chunk.
// Main loop is BARRIER-FREE: per window, 4 contiguous-1KB global b128 loads
// (A-frags, L2-streaming) + LDS reads; p = adj ? max(E1i*E1j, E2i*E2j) : 0
// (rank-1 max factorization, exact); 5 MFMA (4 PV + ones-denominator).
// launch_bounds(256,6): high occupancy is the latency-hiding mechanism.
// Outputs: unnormalized bf16 partial h' + f32 denom partial per chunk.
// ---------------------------------------------------------------------------
__global__ __launch_bounds__(256, 6)
void k_gat(const unsigned* __restrict__ bits,
           const unsigned short* __restrict__ WhTf,
           const float2* __restrict__ Eit, const float* __restrict__ Ejt,
           unsigned short* __restrict__ Pp, float* __restrict__ lsp, int W) {
  extern __shared__ char smem[];
  unsigned* mlds = (unsigned*)smem;                // 64 x 33 u32 = 8448 B
  float* ejlds = (float*)(smem + 8448);            // W*64 floats

  const int t = threadIdx.x;
  const int w = t >> 6, lane = t & 63;
  const int jp = lane & 15, rg = lane >> 4;
  const int bid = blockIdx.x;
  const int c = bid >> 8;
  const int b = (bid >> 6) & 3;
  const int i0 = (bid & 63) * 64;
  const int g0 = c * W;

  // one-time: mask rows -> padded LDS
  {
    const int row = t >> 2;
    const unsigned* src = bits + ((size_t)(i0 + row) << 7) + g0;
    for (int g = (t & 3); g < W; g += 4) mlds[row * 33 + g] = src[g];
  }
  // one-time: Ej chunk -> LDS (W*64 floats)
  {
    const float4* src = (const float4*)(Ejt + ((size_t)b * NN + (size_t)g0 * 32) * 2);
    float4* dst = (float4*)ejlds;
    const int cnt = W * 16;
    for (int k2 = t; k2 < cnt; k2 += 256) dst[k2] = src[k2];
  }

  const float2 ei = Eit[b * NN + i0 + w * 16 + jp];
  const float E1i = ei.x, E2i = ei.y;
  const unsigned short* __restrict__ abase = WhTf + (size_t)g0 * 512 + lane * 8;

  f32x4 acc[4];
#pragma unroll
  for (int ft = 0; ft < 4; ++ft) acc[ft] = (f32x4){0.f, 0.f, 0.f, 0.f};
  f32x4 accd = (f32x4){0.f, 0.f, 0.f, 0.f};
  bf16x8 ones;
#pragma unroll
  for (int e = 0; e < 8; ++e) ones[e] = (short)0x3F80;

  __syncthreads();   // one-time stages complete; no barriers below

  for (int jt = 0; jt < W; ++jt) {
    bf16x8 af[4];
#pragma unroll
    for (int ft = 0; ft < 4; ++ft)
      af[ft] = *(const bf16x8*)(abase + ((((size_t)(b * 4 + ft)) << 7) + jt) * 512);
    const f32x4* __restrict__ ejp = (const f32x4*)(ejlds + jt * 64 + rg * 16);
    const f32x4 q0 = ejp[0], q1 = ejp[1], q2 = ejp[2], q3 = ejp[3];
    const unsigned mb = mlds[(w * 16 + jp) * 33 + jt] >> (rg * 8);

    bf16x8 p;
#pragma unroll
    for (int e = 0; e < 8; ++e) {
      const f32x4 qq = (e < 2) ? q0 : (e < 4) ? q1 : (e < 6) ? q2 : q3;
      const float E1j = qq[(e & 1) * 2];
      const float E2j = qq[(e & 1) * 2 + 1];
      float pv = fmaxf(E1i * E1j, E2i * E2j);   // == exp2(leaky(score))
      pv = ((mb >> e) & 1u) ? pv : 0.0f;        // adjacency mask
      p[e] = bf16s(pv);
    }
    accd = __builtin_amdgcn_mfma_f32_16x16x32_bf16(ones, p, accd, 0, 0, 0);
#pragma unroll
    for (int ft = 0; ft < 4; ++ft)
      acc[ft] = __builtin_amdgcn_mfma_f32_16x16x32_bf16(af[ft], p, acc[ft], 0, 0, 0);
  }

  // store partials: acc[ft][r] = D[f=ft*16+rg*4+r][i = i0+w*16+jp]
  const size_t obase = (((size_t)(c * 4 + b) * NN) + i0 + w * 16 + jp) * 64;
#pragma unroll
  for (int ft = 0; ft < 4; ++ft) {
    s16x4 pk;
#pragma unroll
    for (int r = 0; r < 4; ++r) pk[r] = bf16s(acc[ft][r]);
    *(s16x4*)(Pp + obase + ft * 16 + rg * 4) = pk;
  }
  if (rg == 0)
    lsp[(size_t)(c * 4 + b) * NN + i0 + w * 16 + jp] = accd[0];
}

// ---------------------------------------------------------------------------
// Kernel 3: combine chunk partials, normalize, BatchNorm + residual + ELU.
// ---------------------------------------------------------------------------
__global__ __launch_bounds__(256)
void k_bn(const float* __restrict__ h, const unsigned short* __restrict__ Pp,
          const float* __restrict__ lsp, const float* __restrict__ gamma,
          const float* __restrict__ beta, float* __restrict__ out, int nc) {
  __shared__ float bnp[8][4][2];
  const int t = threadIdx.x;
  const int w = t >> 6, lane = t & 63;   // w = batch
  const int i0 = blockIdx.x * 8;
  float x[8];
#pragma unroll
  for (int ii = 0; ii < 8; ++ii) {
    const int i = i0 + ii;
    float xv = 0.f, lt = 0.f;
    for (int cc = 0; cc < nc; ++cc) {
      xv += bf2f(Pp[((size_t)(cc * 4 + w) * NN + i) * 64 + lane]);
      lt += lsp[(size_t)(cc * 4 + w) * NN + i];
    }
    xv /= lt;
    x[ii] = xv;
    float s1 = xv, s2 = xv * xv;
#pragma unroll
    for (int m = 32; m; m >>= 1) { s1 += __shfl_xor(s1, m); s2 += __shfl_xor(s2, m); }
    if (lane == 0) { bnp[ii][w][0] = s1; bnp[ii][w][1] = s2; }
  }
  __syncthreads();
#pragma unroll
  for (int ii = 0; ii < 8; ++ii) {
    const float t1 = bnp[ii][0][0] + bnp[ii][1][0] + bnp[ii][2][0] + bnp[ii][3][0];
    const float t2 = bnp[ii][0][1] + bnp[ii][1][1] + bnp[ii][2][1] + bnp[ii][3][1];
    const float mean = t1 * (1.f / 256.f);
    const float var  = t2 * (1.f / 256.f) - mean * mean;
    const float sc = gamma[i0 + ii] * rsqrtf(var + 1e-5f);
    const float bt = beta[i0 + ii];
    const size_t off = (((size_t)(w * NN + i0 + ii)) << 6) + lane;
    float o = sc * (x[ii] - mean) + bt + h[off];
    o = o > 0.f ? o : exp2_fast(o * LOG2E) - 1.f;
    out[off] = o;
  }
}

// ---------------------------------------------------------------------------
extern "C" void kernel_launch(void* const* d_in, const int* in_sizes, int n_in,
                              void* d_out, int out_size, void* d_ws, size_t ws_size,
                              hipStream_t stream) {
  (void)in_sizes; (void)n_in; (void)out_size;
  const float* h     = (const float*)d_in[0];
  const int*   adj   = (const int*)d_in[1];
  const float* W     = (const float*)d_in[2];
  const float* a     = (const float*)d_in[3];
  const float* gamma = (const float*)d_in[4];
  const float* beta  = (const float*)d_in[5];
  float* out = (float*)d_out;

  char* ws = (char*)d_ws;
  unsigned short* WhTf = (unsigned short*)ws;                    // 2 MB @ 0
  unsigned* bits = (unsigned*)(ws + (2u << 20));                 // 2 MB @ 2M
  float2* Eit = (float2*)(ws + (4u << 20));                      // 128 KB
  float2* Ejt = (float2*)(ws + (4u << 20) + (128u << 10));       // 128 KB
  float* lsp = (float*)(ws + (4u << 20) + (256u << 10));         // <=256 KB
  unsigned short* Pp = (unsigned short*)(ws + (4u << 20) + (512u << 10)); // nc*2MB

  const size_t base = (4u << 20) + (512u << 10);
  int nc = (ws_size >= base + (8u << 20)) ? 4
         : (ws_size >= base + (4u << 20)) ? 2 : 1;
  const int Wn = 128 / nc;
  const size_t smem = 8448 + (size_t)Wn * 256;

  k_prep<<<2560, 256, 0, stream>>>(h, W, a, adj, WhTf, Eit, Ejt, bits);
  k_gat<<<nc * 256, 256, smem, stream>>>(bits, WhTf, Eit, (const float*)Ejt,
                                         Pp, lsp, Wn);
  k_bn<<<512, 256, 0, stream>>>(h, Pp, lsp, gamma, beta, out, nc);
}

// Round 10
// 58.534 us; speedup vs baseline: 1.1423x; 1.1423x over previous
//
#include <hip/hip_runtime.h>
#include <hip/hip_bf16.h>
#include <math.h>

#define NN 4096
// (1/64) * log2(e)  -- folds 1/sqrt(N) and exp->exp2 conversion
#define SCL 0.022542110013890054f
#define LOG2E 1.4426950408889634f

typedef __attribute__((ext_vector_type(8))) short bf16x8;
typedef __attribute__((ext_vector_type(4))) float f32x4;
typedef __attribute__((ext_vector_type(4))) short s16x4;

__device__ __forceinline__ float exp2_fast(float x) {
  float r; asm("v_exp_f32 %0, %1" : "=v"(r) : "v"(x)); return r;
}
__device__ __forceinline__ short bf16s(float x) {
  __hip_bfloat16 b = __float2bfloat16(x);
  return *(short*)&b;
}
__device__ __forceinline__ float bf2f(unsigned short u) {
  unsigned v = (unsigned)u << 16; return *(float*)&v;
}
__device__ __forceinline__ void gload16(const void* g, void* l) {
  __builtin_amdgcn_global_load_lds(
      (const __attribute__((address_space(1))) unsigned*)g,
      (__attribute__((address_space(3))) unsigned*)l, 16, 0, 0);
}

// ---------------------------------------------------------------------------
// Kernel 1 (fused by block range):
//   blocks [0,2048):    Wh = h@W -> fragment-major WhTf; E-tables (validated).
//   blocks [2048,4096): adj -> bits[i][g], one word per thread, barrier-free:
//     thread reads its own 128 B (8 consecutive int4; L1 merges line halves
//     across lanes), packs 32 LSBs, coalesced word store.
// ---------------------------------------------------------------------------
__global__ __launch_bounds__(256)
void k_prep(const float* __restrict__ h, const float* __restrict__ W,
            const float* __restrict__ a, const int* __restrict__ adj,
            unsigned short* __restrict__ WhTf, float2* __restrict__ Eit,
            float2* __restrict__ Ejt, unsigned* __restrict__ bits) {
  const int t = threadIdx.x;
  const int bi = blockIdx.x;
  if (bi >= 2048) {
    const int ti = (bi - 2048) * 256 + t;      // 0 .. 524287
    const int r = ti >> 7, g = ti & 127;       // row, 32-j word index
    const int4* __restrict__ ap = (const int4*)(adj + ((size_t)r << 12) + (g << 5));
    unsigned m = 0;
#pragma unroll
    for (int q = 0; q < 8; ++q) {
      int4 av = ap[q];
      m |= (unsigned)(av.x & 1) << (q * 4 + 0);
      m |= (unsigned)(av.y & 1) << (q * 4 + 1);
      m |= (unsigned)(av.z & 1) << (q * 4 + 2);
      m |= (unsigned)(av.w & 1) << (q * 4 + 3);
    }
    bits[(size_t)r * 128 + g] = m;
    return;
  }
  // ---- Wh path: 8 rows (same batch) per block ----
  __shared__ float sW[4096];
  __shared__ unsigned short T[64][8];
#pragma unroll
  for (int i = 0; i < 16; ++i) sW[i * 256 + t] = W[i * 256 + t];
  __syncthreads();
  const int wv = t >> 6, lane = t & 63;
  const float a1 = a[lane], a2 = a[64 + lane];
  const int row0 = bi * 8;
  for (int r = 0; r < 2; ++r) {
    const int row = row0 + wv * 2 + r;
    const float* hr = h + (size_t)row * 64;
    float acc = 0.f;
#pragma unroll
    for (int k = 0; k < 64; ++k) acc = fmaf(hr[k], sW[k * 64 + lane], acc);
    T[lane][wv * 2 + r] = (unsigned short)bf16s(acc);
    float r1 = acc * a1, r2 = acc * a2;
#pragma unroll
    for (int sft = 32; sft; sft >>= 1) { r1 += __shfl_xor(r1, sft); r2 += __shfl_xor(r2, sft); }
    if (lane == 0) {
      const float w1s = r1 * SCL, w2s = r2 * SCL;
      Eit[row] = make_float2(exp2_fast(w1s), exp2_fast(0.2f * w1s));
      Ejt[row] = make_float2(exp2_fast(w2s), exp2_fast(0.2f * w2s));
    }
  }
  __syncthreads();
  // fragment-major store (validated): (b, ft, g, lane=rg*16+jp, e) holds
  // Wh[n = g*32 + rg*8 + e][f = ft*16 + jp].
  const int f = t >> 2, jp4 = t & 3;
  const int b = row0 >> 12, n0 = row0 & 4095;
  const int g32 = n0 >> 5, rgq = (n0 >> 3) & 3;
  unsigned v = *(unsigned*)&T[f][jp4 * 2];
  unsigned short* dst = WhTf +
      ((((size_t)(b * 4 + (f >> 4)) << 7) + g32) << 9) +
      ((rgq * 16 + (f & 15)) << 3) + jp4 * 2;
  *(unsigned*)dst = v;
}

// ---------------------------------------------------------------------------
// Kernel 2: masked-softmax attention partials via MFMA, T3+T4 counted-vmcnt
// pipeline. Grid 1024 = 4 chunks x 4 b x 64 i-blocks (64 rows). Block 256 thr
// = 4 waves; wave w owns i-rows [i0+16w,+16) and STAGES fragment ft=w into a
// 4-deep LDS ring via global_load_lds (1 KB per wave per window). Per window:
// issue stage(jt+2); s_waitcnt vmcnt(2) (loads stay 2 deep in flight -- never
// drained); s_barrier; read all 4 af frags + Ej + mask from LDS; p = adj ?
// max(E1i*E1j, E2i*E2j) : 0 (rank-1 max factorization, exact); 5 MFMA.
// Depth-4 ring + 1 barrier/window is race-free: writer targets slot jt+2,
// slowest concurrent reader is at window jt-1 (3 apart mod 4).
// Outputs: unnormalized bf16 partial h' + f32 denom partial per chunk.
// ---------------------------------------------------------------------------
__global__ __launch_bounds__(256, 4)
void k_gat(const unsigned* __restrict__ bits,
           const unsigned short* __restrict__ WhTf,
           const float2* __restrict__ Eit, const float* __restrict__ Ejt,
           unsigned short* __restrict__ Pp, float* __restrict__ lsp) {
  __shared__ unsigned short abuf[4][4][512];   // [slot][ft][lane*8] 16 KB
  __shared__ unsigned mlds[64][33];            // mask rows, padded, 8.4 KB
  __shared__ float ejlds[2048];                // Ej chunk (1024 j pairs), 8 KB

  const int t = threadIdx.x;
  const int w = t >> 6, lane = t & 63;
  const int jp = lane & 15, rg = lane >> 4;
  const int bid = blockIdx.x;
  const int c = bid >> 8;
  const int b = (bid >> 6) & 3;
  const int i0 = (bid & 63) * 64;
  const int g0 = c * 32;

  // one-time: mask rows -> padded LDS
  {
    const int row = t >> 2;
    const unsigned* src = bits + ((size_t)(i0 + row) << 7) + g0;
#pragma unroll
    for (int g = (t & 3); g < 32; g += 4) mlds[row][g] = src[g];
  }
  // one-time: Ej chunk -> LDS (2048 floats)
  {
    const float4* src = (const float4*)(Ejt + ((size_t)b * NN + (size_t)g0 * 32) * 2);
    float4* dst = (float4*)ejlds;
    for (int k2 = t; k2 < 512; k2 += 256) dst[k2] = src[k2];
  }
  // prologue: stage windows 0,1 (wave w stages fragment ft=w)
  const size_t fbase = ((size_t)(b * 4 + w) << 7) + g0;
  gload16(WhTf + ((fbase + 0) << 9) + lane * 8, &abuf[0][w][lane * 8]);
  gload16(WhTf + ((fbase + 1) << 9) + lane * 8, &abuf[1][w][lane * 8]);

  const float2 ei = Eit[b * NN + i0 + w * 16 + jp];
  const float E1i = ei.x, E2i = ei.y;

  f32x4 acc[4];
#pragma unroll
  for (int ft = 0; ft < 4; ++ft) acc[ft] = (f32x4){0.f, 0.f, 0.f, 0.f};
  f32x4 accd = (f32x4){0.f, 0.f, 0.f, 0.f};
  bf16x8 ones;
#pragma unroll
  for (int e = 0; e < 8; ++e) ones[e] = (short)0x3F80;

  __syncthreads();   // one-time stages + prologue stages complete (full drain, once)

  for (int jt = 0; jt < 32; ++jt) {
    // stage window jt+2 (jt>=30 over-reads <=2KB into bits region: unused)
    gload16(WhTf + ((fbase + jt + 2) << 9) + lane * 8,
            &abuf[(jt + 2) & 3][w][lane * 8]);
    asm volatile("s_waitcnt vmcnt(2)" ::: "memory");   // window jt's DMA done
    __builtin_amdgcn_s_barrier();                      // all 4 ft of jt in LDS
    __builtin_amdgcn_sched_barrier(0);

    const int slot = jt & 3;
    bf16x8 af[4];
#pragma unroll
    for (int ft = 0; ft < 4; ++ft)
      af[ft] = *(const bf16x8*)&abuf[slot][ft][lane * 8];
    const f32x4* __restrict__ ejp = (const f32x4*)(ejlds + jt * 64 + rg * 16);
    const f32x4 q0 = ejp[0], q1 = ejp[1], q2 = ejp[2], q3 = ejp[3];
    const unsigned mb = mlds[w * 16 + jp][jt] >> (rg * 8);

    bf16x8 p;
#pragma unroll
    for (int e = 0; e < 8; ++e) {
      const f32x4 qq = (e < 2) ? q0 : (e < 4) ? q1 : (e < 6) ? q2 : q3;
      const float E1j = qq[(e & 1) * 2];
      const float E2j = qq[(e & 1) * 2 + 1];
      float pv = fmaxf(E1i * E1j, E2i * E2j);   // == exp2(leaky(score))
      pv = ((mb >> e) & 1u) ? pv : 0.0f;        // adjacency mask
      p[e] = bf16s(pv);
    }
    accd = __builtin_amdgcn_mfma_f32_16x16x32_bf16(ones, p, accd, 0, 0, 0);
#pragma unroll
    for (int ft = 0; ft < 4; ++ft)
      acc[ft] = __builtin_amdgcn_mfma_f32_16x16x32_bf16(af[ft], p, acc[ft], 0, 0, 0);
  }

  // store partials: acc[ft][r] = D[f=ft*16+rg*4+r][i = i0+w*16+jp]
  const size_t obase = (((size_t)(c * 4 + b) * NN) + i0 + w * 16 + jp) * 64;
#pragma unroll
  for (int ft = 0; ft < 4; ++ft) {
    s16x4 pk;
#pragma unroll
    for (int r = 0; r < 4; ++r) pk[r] = bf16s(acc[ft][r]);
    *(s16x4*)(Pp + obase + ft * 16 + rg * 4) = pk;
  }
  if (rg == 0)
    lsp[(size_t)(c * 4 + b) * NN + i0 + w * 16 + jp] = accd[0];
}

// ---------------------------------------------------------------------------
// Kernel 3: combine chunk partials, normalize, BatchNorm + residual + ELU.
// Grid 2048 (2 nodes/block) for TLP; wave = batch.
// ---------------------------------------------------------------------------
__global__ __launch_bounds__(256)
void k_bn(const float* __restrict__ h, const unsigned short* __restrict__ Pp,
          const float* __restrict__ lsp, const float* __restrict__ gamma,
          const float* __restrict__ beta, float* __restrict__ out) {
  __shared__ float bnp[2][4][2];
  const int t = threadIdx.x;
  const int w = t >> 6, lane = t & 63;   // w = batch
  const int i0 = blockIdx.x * 2;
  float x[2];
#pragma unroll
  for (int ii = 0; ii < 2; ++ii) {
    const int i = i0 + ii;
    float xv = 0.f, lt = 0.f;
#pragma unroll
    for (int cc = 0; cc < 4; ++cc) {
      xv += bf2f(Pp[((size_t)(cc * 4 + w) * NN + i) * 64 + lane]);
      lt += lsp[(size_t)(cc * 4 + w) * NN + i];
    }
    xv /= lt;
    x[ii] = xv;
    float s1 = xv, s2 = xv * xv;
#pragma unroll
    for (int m = 32; m; m >>= 1) { s1 += __shfl_xor(s1, m); s2 += __shfl_xor(s2, m); }
    if (lane == 0) { bnp[ii][w][0] = s1; bnp[ii][w][1] = s2; }
  }
  __syncthreads();
#pragma unroll
  for (int ii = 0; ii < 2; ++ii) {
    const float t1 = bnp[ii][0][0] + bnp[ii][1][0] + bnp[ii][2][0] + bnp[ii][3][0];
    const float t2 = bnp[ii][0][1] + bnp[ii][1][1] + bnp[ii][2][1] + bnp[ii][3][1];
    const float mean = t1 * (1.f / 256.f);
    const float var  = t2 * (1.f / 256.f) - mean * mean;
    const float sc = gamma[i0 + ii] * rsqrtf(var + 1e-5f);
    const float bt = beta[i0 + ii];
    const size_t off = (((size_t)(w * NN + i0 + ii)) << 6) + lane;
    float o = sc * (x[ii] - mean) + bt + h[off];
    o = o > 0.f ? o : exp2_fast(o * LOG2E) - 1.f;
    out[off] = o;
  }
}

// ---------------------------------------------------------------------------
extern "C" void kernel_launch(void* const* d_in, const int* in_sizes, int n_in,
                              void* d_out, int out_size, void* d_ws, size_t ws_size,
                              hipStream_t stream) {
  (void)in_sizes; (void)n_in; (void)out_size; (void)ws_size;
  const float* h     = (const float*)d_in[0];
  const int*   adj   = (const int*)d_in[1];
  const float* W     = (const float*)d_in[2];
  const float* a     = (const float*)d_in[3];
  const float* gamma = (const float*)d_in[4];
  const float* beta  = (const float*)d_in[5];
  float* out = (float*)d_out;

  char* ws = (char*)d_ws;
  unsigned short* WhTf = (unsigned short*)ws;                    // 2 MB @ 0
  unsigned* bits = (unsigned*)(ws + (2u << 20));                 // 2 MB @ 2M
  float2* Eit = (float2*)(ws + (4u << 20));                      // 128 KB
  float2* Ejt = (float2*)(ws + (4u << 20) + (128u << 10));       // 128 KB
  float* lsp = (float*)(ws + (4u << 20) + (256u << 10));         // 256 KB
  unsigned short* Pp = (unsigned short*)(ws + (4u << 20) + (512u << 10)); // 8 MB

  k_prep<<<4096, 256, 0, stream>>>(h, W, a, adj, WhTf, Eit, Ejt, bits);
  k_gat<<<1024, 256, 0, stream>>>(bits, WhTf, Eit, (const float*)Ejt, Pp, lsp);
  k_bn<<<2048, 256, 0, stream>>>(h, Pp, lsp, gamma, beta, out);
}